// Round 1
// baseline (136.680 us; speedup 1.0000x reference)
//
#include <hip/hip_runtime.h>

#define NN 512
#define TT 32
#define HH 8
#define DD 16
#define CCH 128
#define ROW_STRIDE (TT*CCH)   // 4096 floats per node row

// One block per (t,h). 256 threads, each owns 2 q-rows.
// LDS: K2s (folded keys) + Vps (projected values) = exactly 64KB.
__global__ __launch_bounds__(256) void attn_fused(
    const float* __restrict__ vals,
    const float* __restrict__ keys,
    const float* __restrict__ Wq,
    const float* __restrict__ Wk,
    const float* __restrict__ Wv,
    float* __restrict__ obuf)
{
    __shared__ float K2s[NN * DD];   // 32KB  K2[n][d] = sum_dp Kin[n][dp] * M[d][dp]
    __shared__ float Vps[NN * DD];   // 32KB  Vp[n][e] = sum_d Vin[n][d] * Wv[e][d]

    const int tid = threadIdx.x;
    const int t = blockIdx.x >> 3;
    const int h = blockIdx.x & 7;

    // Phase 1: fold matrix M[d][dp] = sum_e Wq[e][d]*Wk[e][dp] -> Vps[0..255]
    //          raw Wv copy -> Vps[256..511]   (Vps region reused as scratch)
    {
        const int d = tid >> 4, dp = tid & 15;
        float acc = 0.f;
        #pragma unroll
        for (int e = 0; e < 16; ++e)
            acc += Wq[e*16 + d] * Wk[e*16 + dp];
        Vps[tid]       = acc;        // M[d][dp]
        Vps[256 + tid] = Wv[tid];    // Wv[e][d] at [256 + e*16 + d]
    }
    __syncthreads();

    // Phase 2: load my 2 rows, project. q rows (raw values) stay in registers.
    float q0[DD], q1[DD], vp0[DD], vp1[DD];
    const size_t cbase = (size_t)t * CCH + h * DD;
    #pragma unroll
    for (int r = 0; r < 2; ++r) {
        const int n = tid + r * 256;
        const float* vrow = vals + (size_t)n * ROW_STRIDE + cbase;
        const float* krow = keys + (size_t)n * ROW_STRIDE + cbase;
        float* q  = r ? q1  : q0;
        float* vp = r ? vp1 : vp0;
        float kr[DD];
        #pragma unroll
        for (int i = 0; i < DD; i += 4) {
            *(float4*)&q[i]  = *(const float4*)(vrow + i);
            *(float4*)&kr[i] = *(const float4*)(krow + i);
        }
        #pragma unroll
        for (int d = 0; d < DD; ++d) {
            float a = 0.f, b = 0.f;
            #pragma unroll
            for (int dp = 0; dp < DD; ++dp) {
                a += kr[dp] * Vps[d*16 + dp];         // M[d][dp]
                b += q[dp]  * Vps[256 + d*16 + dp];   // Wv[d(=e)][dp(=d)]
            }
            K2s[n*DD + d] = a;
            vp[d] = b;   // keep Vp row in regs until scratch region is dead
        }
    }
    __syncthreads();
    // Phase 3: commit Vp rows (overwrites the M/Wv scratch)
    #pragma unroll
    for (int r = 0; r < 2; ++r) {
        const int n = tid + r * 256;
        const float* vp = r ? vp1 : vp0;
        #pragma unroll
        for (int i = 0; i < DD; i += 4)
            *(float4*)&Vps[n*DD + i] = *(const float4*)&vp[i];
    }
    __syncthreads();

    // Main loop: online softmax over all 512 k-nodes, 2 rows/thread.
    float m0 = -3.0e38f, m1 = -3.0e38f, l0 = 0.f, l1 = 0.f;
    float o0[DD], o1[DD];
    #pragma unroll
    for (int i = 0; i < DD; ++i) { o0[i] = 0.f; o1[i] = 0.f; }
    const float scale = 0.08838834764831845f;   // 1/sqrt(128)

    #pragma unroll 2
    for (int k = 0; k < NN; ++k) {
        float kf[DD], vf[DD];
        #pragma unroll
        for (int i = 0; i < DD; i += 4) {
            *(float4*)&kf[i] = *(const float4*)&K2s[k*DD + i];
            *(float4*)&vf[i] = *(const float4*)&Vps[k*DD + i];
        }
        float s0a = 0.f, s0b = 0.f, s1a = 0.f, s1b = 0.f;
        #pragma unroll
        for (int i = 0; i < DD; i += 2) {
            s0a += q0[i]   * kf[i];
            s0b += q0[i+1] * kf[i+1];
            s1a += q1[i]   * kf[i];
            s1b += q1[i+1] * kf[i+1];
        }
        const float s0 = (s0a + s0b) * scale;
        const float s1 = (s1a + s1b) * scale;
        const float mn0 = fmaxf(m0, s0);
        const float mn1 = fmaxf(m1, s1);
        const float c0 = __expf(m0 - mn0);
        const float c1 = __expf(m1 - mn1);
        const float p0 = __expf(s0 - mn0);
        const float p1 = __expf(s1 - mn1);
        l0 = l0 * c0 + p0;
        l1 = l1 * c1 + p1;
        #pragma unroll
        for (int i = 0; i < DD; ++i) {
            o0[i] = o0[i] * c0 + p0 * vf[i];
            o1[i] = o1[i] * c1 + p1 * vf[i];
        }
        m0 = mn0; m1 = mn1;
    }

    // Epilogue: normalize, write O in [n][t][c] layout (c = h*16+e)
    const float inv0 = 1.f / l0, inv1 = 1.f / l1;
    {
        float* orow0 = obuf + (size_t)tid * ROW_STRIDE + cbase;
        float* orow1 = obuf + (size_t)(tid + 256) * ROW_STRIDE + cbase;
        #pragma unroll
        for (int i = 0; i < DD; i += 4) {
            float4 a, b;
            a.x = o0[i+0]*inv0; a.y = o0[i+1]*inv0; a.z = o0[i+2]*inv0; a.w = o0[i+3]*inv0;
            b.x = o1[i+0]*inv1; b.y = o1[i+1]*inv1; b.z = o1[i+2]*inv1; b.w = o1[i+3]*inv1;
            *(float4*)(orow0 + i) = a;
            *(float4*)(orow1 + i) = b;
        }
    }
}

// In-place FC: out[row][e] = bfc[e] + sum_c x[row][c] * Wfc[e][c]
// 64 rows per block; x staged fully in LDS before any write (in-place safe).
__global__ __launch_bounds__(256) void fc_kernel(
    float* __restrict__ io,
    const float* __restrict__ Wfc,
    const float* __restrict__ bfc)
{
    __shared__ float xs[64 * CCH];    // 32KB
    __shared__ float wt[32 * 132];    // 16.9KB, wt[cl][e] padded stride 132

    const int tid = threadIdx.x;
    const int rowbase = blockIdx.x * 64;

    // stage 64 x-rows (coalesced)
    #pragma unroll
    for (int i = 0; i < 8; ++i) {
        const int idx4 = i * 256 + tid;
        *(float4*)&xs[idx4 * 4] = *(const float4*)(io + (size_t)rowbase * CCH + idx4 * 4);
    }

    const int half = tid >> 7;       // 0/1 -> which 4-row subset
    const int e = tid & 127;
    const float be = bfc[e];

    float acc[8][4];
    #pragma unroll
    for (int g = 0; g < 8; ++g)
        #pragma unroll
        for (int r = 0; r < 4; ++r) acc[g][r] = be;

    for (int ct = 0; ct < 4; ++ct) {
        __syncthreads();   // covers xs staging on first iter, wt reuse on later iters
        // stage Wfc column-tile: wt[cl][e2] = Wfc[e2][ct*32+cl]
        #pragma unroll
        for (int i = 0; i < 16; ++i) {
            const int idx = i * 256 + tid;
            const int e2 = idx >> 5, cl = idx & 31;
            wt[cl * 132 + e2] = Wfc[e2 * CCH + ct * 32 + cl];
        }
        __syncthreads();
        #pragma unroll 1
        for (int cc = 0; cc < 32; cc += 4) {
            const float w0 = wt[(cc+0) * 132 + e];
            const float w1 = wt[(cc+1) * 132 + e];
            const float w2 = wt[(cc+2) * 132 + e];
            const float w3 = wt[(cc+3) * 132 + e];
            #pragma unroll
            for (int g = 0; g < 8; ++g) {
                #pragma unroll
                for (int r = 0; r < 4; ++r) {
                    const float4 xv = *(const float4*)&xs[(g*8 + half*4 + r) * CCH + ct*32 + cc];
                    acc[g][r] += w0*xv.x + w1*xv.y + w2*xv.z + w3*xv.w;
                }
            }
        }
    }

    #pragma unroll
    for (int g = 0; g < 8; ++g) {
        #pragma unroll
        for (int r = 0; r < 4; ++r) {
            io[(size_t)(rowbase + g*8 + half*4 + r) * CCH + e] = acc[g][r];
        }
    }
}

extern "C" void kernel_launch(void* const* d_in, const int* in_sizes, int n_in,
                              void* d_out, int out_size, void* d_ws, size_t ws_size,
                              hipStream_t stream)
{
    const float* vals = (const float*)d_in[0];
    const float* keys = (const float*)d_in[1];
    // d_in[2] = query  (UNUSED: reference builds q from `values` — source bug kept)
    // d_in[3] = heads  (fixed = 8)
    const float* Wq  = (const float*)d_in[4];
    const float* Wk  = (const float*)d_in[5];
    const float* Wv  = (const float*)d_in[6];
    const float* Wfc = (const float*)d_in[7];
    const float* bfc = (const float*)d_in[8];
    float* out = (float*)d_out;

    attn_fused<<<dim3(TT * HH), dim3(256), 0, stream>>>(vals, keys, Wq, Wk, Wv, out);
    fc_kernel<<<dim3(256), dim3(256), 0, stream>>>(out, Wfc, bfc);
}

// Round 2
// 67.705 us; speedup vs baseline: 2.0188x; 2.0188x over previous
//
#include <hip/hip_runtime.h>

typedef __bf16 bf16x8 __attribute__((ext_vector_type(8)));
typedef float  f32x16 __attribute__((ext_vector_type(16)));

#define NN 512
#define TT 32
#define HH 8
#define CCH 128
#define RS (TT*CCH)   // 4096 floats per node row

__device__ __forceinline__ unsigned cvt_pk_bf16(float a, float b) {
    unsigned r;
    asm("v_cvt_pk_bf16_f32 %0, %1, %2" : "=v"(r) : "v"(a), "v"(b));
    return r;
}

// One block per (t,h). 4 waves; wave owns 128 q-rows (4 tiles of 32).
// S^T = mfma(A=K2 32x16, B=Q 16x32)  -> lane owns one q-column, 16 k-rows.
// PV:  out^T = mfma(A=Vp^T 32(e)x16(k), B=P^T 16(k)x32(q)); A row e=16 = ones
//      so acc reg8 (lo lanes) accumulates the softmax denominator for free.
__global__ __launch_bounds__(256) void attn_mfma(
    const float* __restrict__ vals,
    const float* __restrict__ keys,
    const float* __restrict__ Wq,
    const float* __restrict__ Wk,
    const float* __restrict__ Wv,
    float* __restrict__ obuf)
{
    __shared__ uint4 k2f[16*64];   // 16KB  A-frags for S: K2[ktile]
    __shared__ uint4 vpf[32*64];   // 32KB  A-frags for PV: Vp^T[ktile][khalf] (e rows, zero-padded, e16=ones)
    __shared__ float wlds[512];    // 2KB   M (scaled) + Wv

    const int tid  = threadIdx.x;
    const int lane = tid & 63;
    const int wv   = tid >> 6;
    const int t = blockIdx.x >> 3;
    const int h = blockIdx.x & 7;
    const size_t cb0 = (size_t)t*CCH + h*16;

    // Phase A: M[d][dp] = sum_e Wq[e][d]*Wk[e][dp], scaled by (1/sqrt(128))*log2(e)
    {
        const int d = tid >> 4, dp = tid & 15;
        float a = 0.f;
        #pragma unroll
        for (int e = 0; e < 16; ++e) a = fmaf(Wq[e*16+d], Wk[e*16+dp], a);
        wlds[tid]       = a * 0.12751744503131863f;
        wlds[256 + tid] = Wv[tid];
    }
    // Vp-frag pad: lane row e==16 -> bf16 ones (denominator), e=17..31 -> zeros
    {
        const uint4 z4 = make_uint4(0u,0u,0u,0u);
        const uint4 o4 = make_uint4(0x3F803F80u,0x3F803F80u,0x3F803F80u,0x3F803F80u);
        for (int i = tid; i < 32*32; i += 256) {
            const int f = i >> 5, j = i & 31;
            const int ln = (j < 16) ? (16 + j) : (32 + j);   // lanes 16..31 / 48..63
            vpf[f*64 + ln] = ((ln & 31) == 16) ? o4 : z4;
        }
    }
    __syncthreads();

    // Phase B: each thread projects 2 node-rows into K2 + Vp^T fragments (bf16)
    unsigned short* vph = (unsigned short*)vpf;
    #pragma unroll
    for (int rr = 0; rr < 2; ++rr) {
        const int n = tid + rr*256;
        const float* vrow = vals + (size_t)n*RS + cb0;
        const float* krow = keys + (size_t)n*RS + cb0;
        float kr[16], vr[16];
        #pragma unroll
        for (int i = 0; i < 16; i += 4) {
            *(float4*)&kr[i] = *(const float4*)(krow + i);
            *(float4*)&vr[i] = *(const float4*)(vrow + i);
        }
        float k2[16], vp[16];
        #pragma unroll
        for (int d = 0; d < 16; ++d) {
            float a = 0.f, b = 0.f;
            #pragma unroll
            for (int dp = 0; dp < 16; ++dp) {
                a = fmaf(kr[dp], wlds[d*16+dp], a);
                b = fmaf(vr[dp], wlds[256 + d*16+dp], b);
            }
            k2[d] = a; vp[d] = b;
        }
        const int kt = n >> 5, r = n & 31;
        uint4 lo4, hi4;
        lo4.x = cvt_pk_bf16(k2[0],k2[1]);   lo4.y = cvt_pk_bf16(k2[2],k2[3]);
        lo4.z = cvt_pk_bf16(k2[4],k2[5]);   lo4.w = cvt_pk_bf16(k2[6],k2[7]);
        hi4.x = cvt_pk_bf16(k2[8],k2[9]);   hi4.y = cvt_pk_bf16(k2[10],k2[11]);
        hi4.z = cvt_pk_bf16(k2[12],k2[13]); hi4.w = cvt_pk_bf16(k2[14],k2[15]);
        k2f[kt*64 + r]      = lo4;   // lane r (k-row), d 0..7
        k2f[kt*64 + r + 32] = hi4;   // lane r+32,     d 8..15
        // Vp^T scatter: frag=(kt,khalf), lane = lg*32 + e, halfword ii
        const int f  = kt*2 + (r >> 4);
        const int lg = (r >> 3) & 1;
        const int ii = r & 7;
        #pragma unroll
        for (int e = 0; e < 16; ++e)
            vph[(size_t)(f*64 + lg*32 + e)*8 + ii] =
                (unsigned short)(cvt_pk_bf16(vp[e], vp[e]) & 0xffffu);
    }
    __syncthreads();

    // Q B-frags straight from global (raw `values` rows — the source bug)
    bf16x8 qfb[4];
    const int qr = lane & 31;
    const int dh = (lane >> 5) * 8;
    #pragma unroll
    for (int j = 0; j < 4; ++j) {
        const int n = wv*128 + j*32 + qr;
        const float* p = vals + (size_t)n*RS + cb0 + dh;
        const float4 qa = *(const float4*)p;
        const float4 qb = *(const float4*)(p + 4);
        uint4 u;
        u.x = cvt_pk_bf16(qa.x, qa.y);
        u.y = cvt_pk_bf16(qa.z, qa.w);
        u.z = cvt_pk_bf16(qb.x, qb.y);
        u.w = cvt_pk_bf16(qb.z, qb.w);
        qfb[j] = __builtin_bit_cast(bf16x8, u);
    }

    f32x16 acc[4];
    #pragma unroll
    for (int j = 0; j < 4; ++j)
        #pragma unroll
        for (int r2 = 0; r2 < 16; ++r2) acc[j][r2] = 0.f;
    float mrun[4] = {-3.0e38f, -3.0e38f, -3.0e38f, -3.0e38f};
    const bool lohalf = lane < 32;

    for (int kt = 0; kt < 16; ++kt) {
        const bf16x8 ak  = __builtin_bit_cast(bf16x8, k2f[kt*64 + lane]);
        const bf16x8 av0 = __builtin_bit_cast(bf16x8, vpf[(kt*2+0)*64 + lane]);
        const bf16x8 av1 = __builtin_bit_cast(bf16x8, vpf[(kt*2+1)*64 + lane]);
        #pragma unroll
        for (int j = 0; j < 4; ++j) {
            f32x16 zc;
            #pragma unroll
            for (int r2 = 0; r2 < 16; ++r2) zc[r2] = 0.f;
            f32x16 s = __builtin_amdgcn_mfma_f32_32x32x16_bf16(ak, qfb[j], zc, 0, 0, 0);
            // tile max over 32 k: in-lane tree (15 fmax) + pair-lane swap
            const float t01 = fmaxf(s[0], s[1]),   t23 = fmaxf(s[2], s[3]);
            const float t45 = fmaxf(s[4], s[5]),   t67 = fmaxf(s[6], s[7]);
            const float t89 = fmaxf(s[8], s[9]),   tab = fmaxf(s[10], s[11]);
            const float tcd = fmaxf(s[12], s[13]), tef = fmaxf(s[14], s[15]);
            float pm = fmaxf(fmaxf(fmaxf(t01,t23), fmaxf(t45,t67)),
                             fmaxf(fmaxf(t89,tab), fmaxf(tcd,tef)));
            pm = fmaxf(pm, __shfl_xor(pm, 32));
            const float mn = fmaxf(mrun[j], pm);
            const float cs = exp2f(mrun[j] - mn);   // first iter: exp2(-huge) = 0
            mrun[j] = mn;
            // P = 2^(s-mn) packed to bf16 pairs (consecutive k within each word)
            const unsigned w0 = cvt_pk_bf16(exp2f(s[0]-mn),  exp2f(s[1]-mn));
            const unsigned w1 = cvt_pk_bf16(exp2f(s[2]-mn),  exp2f(s[3]-mn));
            const unsigned w2 = cvt_pk_bf16(exp2f(s[4]-mn),  exp2f(s[5]-mn));
            const unsigned w3 = cvt_pk_bf16(exp2f(s[6]-mn),  exp2f(s[7]-mn));
            const unsigned w4 = cvt_pk_bf16(exp2f(s[8]-mn),  exp2f(s[9]-mn));
            const unsigned w5 = cvt_pk_bf16(exp2f(s[10]-mn), exp2f(s[11]-mn));
            const unsigned w6 = cvt_pk_bf16(exp2f(s[12]-mn), exp2f(s[13]-mn));
            const unsigned w7 = cvt_pk_bf16(exp2f(s[14]-mn), exp2f(s[15]-mn));
            // online rescale (regs 0..7 = outputs, reg8 = denominator; 9..15 stay 0)
            #pragma unroll
            for (int r2 = 0; r2 < 9; ++r2) acc[j][r2] *= cs;
            // redistribute words across the lane/lane+32 pair -> P^T B-frags
            const unsigned x0 = __shfl_xor(w0, 32), x1 = __shfl_xor(w1, 32);
            const unsigned x2 = __shfl_xor(w2, 32), x3 = __shfl_xor(w3, 32);
            const unsigned x4 = __shfl_xor(w4, 32), x5 = __shfl_xor(w5, 32);
            const unsigned x6 = __shfl_xor(w6, 32), x7 = __shfl_xor(w7, 32);
            uint4 pb0, pb1;
            pb0.x = lohalf ? w0 : x2;   // k(0,1)   | k(8,9)
            pb0.y = lohalf ? w1 : x3;   // k(2,3)   | k(10,11)
            pb0.z = lohalf ? x0 : w2;   // k(4,5)   | k(12,13)
            pb0.w = lohalf ? x1 : w3;   // k(6,7)   | k(14,15)
            pb1.x = lohalf ? w4 : x6;   // k(16,17) | k(24,25)
            pb1.y = lohalf ? w5 : x7;   // k(18,19) | k(26,27)
            pb1.z = lohalf ? x4 : w6;   // k(20,21) | k(28,29)
            pb1.w = lohalf ? x5 : w7;   // k(22,23) | k(30,31)
            acc[j] = __builtin_amdgcn_mfma_f32_32x32x16_bf16(av0, __builtin_bit_cast(bf16x8, pb0), acc[j], 0, 0, 0);
            acc[j] = __builtin_amdgcn_mfma_f32_32x32x16_bf16(av1, __builtin_bit_cast(bf16x8, pb1), acc[j], 0, 0, 0);
        }
    }

    // Epilogue: out^T rows e: lo lanes regs0..3 -> e0..3, regs4..7 -> e8..11;
    // hi lanes e4..7 / e12..15. Denominator = lo-lane reg8.
    #pragma unroll
    for (int j = 0; j < 4; ++j) {
        float den = acc[j][8];
        const float ds = __shfl_xor(den, 32);
        if (!lohalf) den = ds;
        const float inv = 1.f / den;
        const int n = wv*128 + j*32 + qr;
        float* orow = obuf + (size_t)n*RS + cb0 + (lohalf ? 0 : 4);
        float4 o0, o1;
        o0.x = acc[j][0]*inv; o0.y = acc[j][1]*inv; o0.z = acc[j][2]*inv; o0.w = acc[j][3]*inv;
        o1.x = acc[j][4]*inv; o1.y = acc[j][5]*inv; o1.z = acc[j][6]*inv; o1.w = acc[j][7]*inv;
        *(float4*)orow       = o0;
        *(float4*)(orow + 8) = o1;
    }
}

// In-place FC: 32 rows/block (512 blocks), x staged in LDS before any write.
__global__ __launch_bounds__(256) void fc_kernel(
    float* __restrict__ io,
    const float* __restrict__ Wfc,
    const float* __restrict__ bfc)
{
    __shared__ float xs[32 * CCH];    // 16KB
    __shared__ float wt[32 * 132];    // 16.9KB padded

    const int tid = threadIdx.x;
    const int rowbase = blockIdx.x * 32;

    #pragma unroll
    for (int i = 0; i < 4; ++i) {
        const int idx4 = i * 256 + tid;
        *(float4*)&xs[idx4 * 4] = *(const float4*)(io + (size_t)rowbase * CCH + idx4 * 4);
    }

    const int half = tid >> 7;
    const int e = tid & 127;
    const float be = bfc[e];

    float acc[4][4];
    #pragma unroll
    for (int g = 0; g < 4; ++g)
        #pragma unroll
        for (int r = 0; r < 4; ++r) acc[g][r] = be;

    for (int ct = 0; ct < 4; ++ct) {
        __syncthreads();
        #pragma unroll
        for (int i = 0; i < 16; ++i) {
            const int idx = i * 256 + tid;
            const int e2 = idx >> 5, cl = idx & 31;
            wt[cl * 132 + e2] = Wfc[e2 * CCH + ct * 32 + cl];
        }
        __syncthreads();
        #pragma unroll 1
        for (int cc = 0; cc < 32; cc += 4) {
            const float w0 = wt[(cc+0) * 132 + e];
            const float w1 = wt[(cc+1) * 132 + e];
            const float w2 = wt[(cc+2) * 132 + e];
            const float w3 = wt[(cc+3) * 132 + e];
            #pragma unroll
            for (int g = 0; g < 4; ++g) {
                #pragma unroll
                for (int r = 0; r < 4; ++r) {
                    const float4 xv = *(const float4*)&xs[(g*8 + half*4 + r) * CCH + ct*32 + cc];
                    acc[g][r] += w0*xv.x + w1*xv.y + w2*xv.z + w3*xv.w;
                }
            }
        }
    }

    #pragma unroll
    for (int g = 0; g < 4; ++g)
        #pragma unroll
        for (int r = 0; r < 4; ++r)
            io[(size_t)(rowbase + g*8 + half*4 + r) * CCH + e] = acc[g][r];
}

extern "C" void kernel_launch(void* const* d_in, const int* in_sizes, int n_in,
                              void* d_out, int out_size, void* d_ws, size_t ws_size,
                              hipStream_t stream)
{
    const float* vals = (const float*)d_in[0];
    const float* keys = (const float*)d_in[1];
    // d_in[2] = query (unused — reference builds q from `values`)
    // d_in[3] = heads (fixed 8)
    const float* Wq  = (const float*)d_in[4];
    const float* Wk  = (const float*)d_in[5];
    const float* Wv  = (const float*)d_in[6];
    const float* Wfc = (const float*)d_in[7];
    const float* bfc = (const float*)d_in[8];
    float* out = (float*)d_out;

    attn_mfma<<<dim3(TT * HH), dim3(256), 0, stream>>>(vals, keys, Wq, Wk, Wv, out);
    fc_kernel<<<dim3(512), dim3(256), 0, stream>>>(out, Wfc, bfc);
}